// Round 6
// baseline (410.569 us; speedup 1.0000x reference)
//
#include <hip/hip_runtime.h>

// Problem constants (from reference)
#define B_     256
#define M_     64
#define T_     1200
#define FT_    10
#define K_     17
#define PAD_   8
#define POOLK_ 75
#define POOLS_ 15
#define TP_    76            // pooled length
#define NSEG_  80            // segments of 15
#define FEAT_  (FT_*TP_)     // 760
#define XLEN_  1312          // padded x~: [0..7]=0, [8..1207]=x, [1208..1311]=0 (covers idx 1295 max)
#define NQT_   5             // 5 N-tiles of 16 q's (80 q >= 75 needed)

typedef _Float16 f16;
typedef f16   f16x4 __attribute__((ext_vector_type(4)));
typedef f16   f16x8 __attribute__((ext_vector_type(8)));
typedef float f32x4 __attribute__((ext_vector_type(4)));

// Toeplitz-MFMA conv: t = 256*qt + 16n + r ;  y[t] = sum_kk A_f[r][kk] * x~[256qt+16n+kk]
// A_f[r][kk] = w[f][kk-r] (zero outside 0..16); kk = 8*(lane>>4)+j, r/n = lane&15.
// Split precision: x = xh+xl, w = wh+wl (f16); y = wh*xh + wh*xl + wl*xh (+fp32 bias in C).
__global__ __launch_bounds__(256, 4)
void ChannelScorer_Distributed_39024072851482_kernel(
    const float* __restrict__ x,      // (B,1,M,T) -> row-major (B*M, T)
    const float* __restrict__ conv_w, // (FT,1,K) = 170
    const float* __restrict__ conv_b, // (FT,)
    const float* __restrict__ lin_w,  // (M, FEAT)
    const float* __restrict__ lin_b,  // (M,)
    float* __restrict__ out)          // (B,M,1) -> 16384
{
    __shared__ __align__(16) f16 xh[2][XLEN_];     // 5.1 KB
    __shared__ __align__(16) f16 xl[2][XLEN_];     // 5.1 KB
    __shared__ __align__(16) f16 Ah[FT_][64][8];   // 10.2 KB  [f][khi*16+r][j]
    __shared__ __align__(16) f16 Al[FT_][64][8];   // 10.2 KB
    __shared__ float S[2][FT_*NSEG_];              // 6.4 KB segment sums
    __shared__ float red[4];
    // total ~37.4 KB -> 4 blocks/CU

    const int tid = threadIdx.x;
    const int r0  = blockIdx.x * 2;               // two rows per block

    // ---- zero S ----
    for (int i = tid; i < 2*FT_*NSEG_; i += 256) (&S[0][0])[i] = 0.f;

    // ---- stage x -> split f16 (xh, xl), zero-padded ----
    for (int i = tid; i < 2*(XLEN_/4); i += 256) {          // 656 float4 tasks
        const int rl = i / (XLEN_/4);
        const int e  = i - rl*(XLEN_/4);                    // 0..327
        float4 v = make_float4(0.f, 0.f, 0.f, 0.f);
        if (e >= 2 && e <= 301)                             // x~[4e..4e+3] = x[4e-8..4e-5]
            v = ((const float4*)(x + (size_t)(r0+rl)*T_))[e-2];
        f16 h0=(f16)v.x, h1=(f16)v.y, h2=(f16)v.z, h3=(f16)v.w;
        f16 l0=(f16)(v.x-(float)h0), l1=(f16)(v.y-(float)h1),
            l2=(f16)(v.z-(float)h2), l3=(f16)(v.w-(float)h3);
        *(f16x4*)&xh[rl][4*e] = (f16x4){h0,h1,h2,h3};
        *(f16x4*)&xl[rl][4*e] = (f16x4){l0,l1,l2,l3};
    }

    // ---- build Toeplitz A fragments in LDS ----
    for (int i = tid; i < FT_*64; i += 256) {               // 640 tasks
        const int f = i >> 6;
        const int l6 = i & 63;                              // khi*16 + r
        const int khi = l6 >> 4, r = l6 & 15;
        f16x8 hv, lv;
        #pragma unroll
        for (int j = 0; j < 8; ++j) {
            const int d = 8*khi + j - r;                    // kk - r
            const float wv = (d >= 0 && d < K_) ? conv_w[f*K_ + d] : 0.f;
            const f16 h = (f16)wv;
            hv[j] = h; lv[j] = (f16)(wv - (float)h);
        }
        *(f16x8*)&Ah[f][l6][0] = hv;
        *(f16x8*)&Al[f][l6][0] = lv;
    }
    __syncthreads();

    // ---- conv via MFMA: wave = (row_local, f-half) -> 5 filters x 5 qtiles x 3 mfma ----
    const int lane = tid & 63, wid = tid >> 6;
    const int rowl = wid & 1, fh = wid >> 1;                // fh*5 .. fh*5+4
    const int boff = 16*(lane & 15) + 8*(lane >> 4);        // B-frag sample offset
    f16x8 bh[NQT_], bl[NQT_];
    #pragma unroll
    for (int qt = 0; qt < NQT_; ++qt) {
        bh[qt] = *(const f16x8*)&xh[rowl][256*qt + boff];
        bl[qt] = *(const f16x8*)&xl[rowl][256*qt + boff];
    }
    const int t_base = 16*(lane & 15) + 4*(lane >> 4);      // t = 256qt + t_base + j

    #pragma unroll 1
    for (int fi = 0; fi < 5; ++fi) {
        const int f = fh*5 + fi;
        const f16x8 ah = *(const f16x8*)&Ah[f][lane][0];
        const f16x8 al = *(const f16x8*)&Al[f][lane][0];
        const float bf = conv_b[f];                         // wave-uniform -> s_load
        float* Srow = &S[rowl][f*NSEG_];
        #pragma unroll
        for (int qt = 0; qt < NQT_; ++qt) {
            f32x4 acc = {bf, bf, bf, bf};
            acc = __builtin_amdgcn_mfma_f32_16x16x32_f16(ah, bh[qt], acc, 0, 0, 0);
            acc = __builtin_amdgcn_mfma_f32_16x16x32_f16(ah, bl[qt], acc, 0, 0, 0);
            acc = __builtin_amdgcn_mfma_f32_16x16x32_f16(al, bh[qt], acc, 0, 0, 0);
            // square + scatter into 15-wide segments (lane's 4 t's span <=2 segs)
            const int t0 = 256*qt + t_base;
            const int s0 = (t0 * 4370) >> 16;               // t0/15, valid t0<1280
            const int sE = ((t0+3) * 4370) >> 16;
            const float q0 = acc[0]*acc[0], q1 = acc[1]*acc[1],
                        q2 = acc[2]*acc[2], q3 = acc[3]*acc[3];
            if (s0 == sE) {
                if (s0 < NSEG_) atomicAdd(&Srow[s0], q0+q1+q2+q3);
            } else {
                const int c = 15*(s0+1) - t0;               // 1..3 elems in s0
                float p0 = q0, p1 = 0.f;
                if (c > 1) p0 += q1; else p1 += q1;
                if (c > 2) p0 += q2; else p1 += q2;
                p1 += q3;
                if (s0     < NSEG_) atomicAdd(&Srow[s0],   p0);
                if (s0 + 1 < NSEG_) atomicAdd(&Srow[s0+1], p1);
            }
        }
    }
    __syncthreads();

    // ---- pool(5 segs) -> log -> dot with lin_w, per row ----
    #pragma unroll 1
    for (int rl = 0; rl < 2; ++rl) {
        const int row = r0 + rl, m = row & (M_-1);
        float partial = 0.f;
        const float* lw = lin_w + (size_t)m * FEAT_;
        for (int i = tid; i < FEAT_; i += 256) {
            const int f = i / TP_;
            const int p = i - f * TP_;
            const float* Sp = &S[rl][f*NSEG_ + p];
            float v = (Sp[0] + Sp[1] + Sp[2] + Sp[3] + Sp[4]) * (1.0f/POOLK_);
            v = fmaxf(v, 1e-10f);
            partial = fmaf(__logf(v), lw[i], partial);
        }
        #pragma unroll
        for (int off = 32; off > 0; off >>= 1)
            partial += __shfl_down(partial, off, 64);
        if ((tid & 63) == 0) red[tid >> 6] = partial;
        __syncthreads();
        if (tid == 0)
            out[row] = red[0] + red[1] + red[2] + red[3] + lin_b[m];
        __syncthreads();                                    // red reused next row
    }
}

extern "C" void kernel_launch(void* const* d_in, const int* in_sizes, int n_in,
                              void* d_out, int out_size, void* d_ws, size_t ws_size,
                              hipStream_t stream) {
    const float* x      = (const float*)d_in[0];
    const float* conv_w = (const float*)d_in[1];
    const float* conv_b = (const float*)d_in[2];
    const float* lin_w  = (const float*)d_in[3];
    const float* lin_b  = (const float*)d_in[4];
    float* out = (float*)d_out;

    dim3 grid((B_ * M_) / 2);       // 8192 blocks, 2 rows each
    dim3 block(256);                // 4 waves
    ChannelScorer_Distributed_39024072851482_kernel<<<grid, block, 0, stream>>>(
        x, conv_w, conv_b, lin_w, lin_b, out);
}

// Round 7
// 205.848 us; speedup vs baseline: 1.9945x; 1.9945x over previous
//
#include <hip/hip_runtime.h>

// Problem constants (from reference)
#define B_     256
#define M_     64
#define T_     1200
#define FT_    10
#define K_     17
#define POOLK_ 75
#define POOLS_ 15
#define TP_    76            // pooled length
#define NSEG_  80            // segments of 15
#define FEAT_  (FT_*TP_)     // 760
#define XLEN_  1312          // padded x~: [0..7]=0, [8..1207]=x, rest 0
#define NQT_   5             // 5 N-tiles of 16 q's (80 q >= 75 needed)

typedef _Float16 f16;
typedef f16   f16x4 __attribute__((ext_vector_type(4)));
typedef f16   f16x8 __attribute__((ext_vector_type(8)));
typedef float f32x4 __attribute__((ext_vector_type(4)));

// Toeplitz-MFMA conv (verified r6): t = 256qt + 16n + r; y = A_f * x~ tiles,
// A_f[r][kk] = w[f][kk-r].  Split precision y = wh*xh + wh*xl + wl*xh + b.
// r7 change: LDS-atomic scatter (r6 bottleneck: ~6-way ds_add serialization,
// VALUBusy 19%) -> wave-private y2 scratch + conflict-free segment gather.
__global__ __launch_bounds__(256, 4)
void ChannelScorer_Distributed_39024072851482_kernel(
    const float* __restrict__ x,      // (B,1,M,T) -> row-major (B*M, T)
    const float* __restrict__ conv_w, // (FT,1,K) = 170
    const float* __restrict__ conv_b, // (FT,)
    const float* __restrict__ lin_w,  // (M, FEAT)
    const float* __restrict__ lin_b,  // (M,)
    float* __restrict__ out)          // (B,M,1) -> 16384
{
    __shared__ __align__(16) f16 xh[2][XLEN_];   // 5.25 KB
    __shared__ __align__(16) f16 xl[2][XLEN_];   // 5.25 KB
    __shared__ float wsm[FT_*K_];                // 680 B
    __shared__ float y2[4][1280];                // 20.5 KB wave-private squared-y
    __shared__ float S[2][FT_*NSEG_];            // 6.4 KB segment sums
    __shared__ float red[4];
    // total ~37.2 KB -> 4 blocks/CU (16 waves)

    const int tid = threadIdx.x;
    const int r0  = blockIdx.x * 2;              // two rows per block

    // ---- stage x -> split f16 (xh, xl), zero-padded ----
    for (int i = tid; i < 2*(XLEN_/4); i += 256) {          // 656 float4 tasks
        const int rl = i / (XLEN_/4);
        const int e  = i - rl*(XLEN_/4);                    // 0..327
        float4 v = make_float4(0.f, 0.f, 0.f, 0.f);
        if (e >= 2 && e <= 301)                             // x~[4e..4e+3] = x[4e-8..4e-5]
            v = ((const float4*)(x + (size_t)(r0+rl)*T_))[e-2];
        f16 h0=(f16)v.x, h1=(f16)v.y, h2=(f16)v.z, h3=(f16)v.w;
        f16 l0=(f16)(v.x-(float)h0), l1=(f16)(v.y-(float)h1),
            l2=(f16)(v.z-(float)h2), l3=(f16)(v.w-(float)h3);
        *(f16x4*)&xh[rl][4*e] = (f16x4){h0,h1,h2,h3};
        *(f16x4*)&xl[rl][4*e] = (f16x4){l0,l1,l2,l3};
    }
    for (int i = tid; i < FT_*K_; i += 256) wsm[i] = conv_w[i];
    __syncthreads();

    const int lane = tid & 63, wid = tid >> 6;
    const int rowl = wid & 1, fh = wid >> 1;     // this wave: row rowl, filters fh*5..fh*5+4
    const int r   = lane & 15;                   // A-row / C-col component
    const int khi = lane >> 4;                   // k-quarter

    // ---- build Toeplitz A fragments in REGISTERS (r6 kept them in 20KB LDS) ----
    f16x8 ahf[NQT_], alf[NQT_];                  // 5 filters x (hi,lo)
    #pragma unroll
    for (int fi = 0; fi < 5; ++fi) {
        const int f = fh*5 + fi;
        #pragma unroll
        for (int j = 0; j < 8; ++j) {
            const int d = 8*khi + j - r;         // kk - r
            const float wv = (d >= 0 && d < K_) ? wsm[f*K_ + d] : 0.f;
            const f16 h = (f16)wv;
            ahf[fi][j] = h;
            alf[fi][j] = (f16)(wv - (float)h);
        }
    }

    // ---- B fragments: col n = lane&15, kk = 8*khi + j ----
    const int boff = 16*(lane & 15) + 8*khi;
    f16x8 bh[NQT_], bl[NQT_];
    #pragma unroll
    for (int qt = 0; qt < NQT_; ++qt) {
        bh[qt] = *(const f16x8*)&xh[rowl][256*qt + boff];
        bl[qt] = *(const f16x8*)&xl[rowl][256*qt + boff];
    }

    const int tb = 16*(lane & 15) + 4*khi;       // C/D: 4 consecutive t = 256qt+tb+j
    float* yw = y2[wid];                         // wave-private scratch

    #pragma unroll
    for (int fi = 0; fi < 5; ++fi) {
        const int f = fh*5 + fi;
        const float bf = conv_b[f];
        // conv for all 5 q-tiles of this filter -> squared y into scratch
        #pragma unroll
        for (int qt = 0; qt < NQT_; ++qt) {
            f32x4 acc = {bf, bf, bf, bf};
            acc = __builtin_amdgcn_mfma_f32_16x16x32_f16(ahf[fi], bh[qt], acc, 0, 0, 0);
            acc = __builtin_amdgcn_mfma_f32_16x16x32_f16(ahf[fi], bl[qt], acc, 0, 0, 0);
            acc = __builtin_amdgcn_mfma_f32_16x16x32_f16(alf[fi], bh[qt], acc, 0, 0, 0);
            f32x4 q = {acc[0]*acc[0], acc[1]*acc[1], acc[2]*acc[2], acc[3]*acc[3]};
            *(f32x4*)&yw[256*qt + tb] = q;       // wave writes a permutation of
        }                                        // 256 consecutive dwords: conflict-free
        // segment gather-reduce (wave-private, no barrier, no atomics):
        // lane l sums y2w[15l..15l+14]; stride 15 coprime 32 banks -> free.
        {
            const int base = 15*lane;            // segs 0..63
            float a0=yw[base+0]+yw[base+1], a1=yw[base+2]+yw[base+3],
                  a2=yw[base+4]+yw[base+5], a3=yw[base+6]+yw[base+7],
                  a4=yw[base+8]+yw[base+9], a5=yw[base+10]+yw[base+11],
                  a6=yw[base+12]+yw[base+13], a7=yw[base+14];
            S[rowl][f*NSEG_ + lane] = ((a0+a1)+(a2+a3)) + ((a4+a5)+(a6+a7));
            if (lane < 16) {                     // segs 64..79 (t 960..1199)
                const int b2 = 960 + 15*lane;
                float c0=yw[b2+0]+yw[b2+1], c1=yw[b2+2]+yw[b2+3],
                      c2=yw[b2+4]+yw[b2+5], c3=yw[b2+6]+yw[b2+7],
                      c4=yw[b2+8]+yw[b2+9], c5=yw[b2+10]+yw[b2+11],
                      c6=yw[b2+12]+yw[b2+13], c7=yw[b2+14];
                S[rowl][f*NSEG_ + 64 + lane] = ((c0+c1)+(c2+c3)) + ((c4+c5)+(c6+c7));
            }
        }
    }
    __syncthreads();

    // ---- pool(5 segs) -> log -> dot with lin_w, per row (r3-verified epilogue) ----
    #pragma unroll 1
    for (int rl = 0; rl < 2; ++rl) {
        const int row = r0 + rl, m = row & (M_-1);
        float partial = 0.f;
        const float* lw = lin_w + (size_t)m * FEAT_;
        for (int i = tid; i < FEAT_; i += 256) {
            const int f = i / TP_;
            const int p = i - f * TP_;
            const float* Sp = &S[rl][f*NSEG_ + p];
            float v = (Sp[0] + Sp[1] + Sp[2] + Sp[3] + Sp[4]) * (1.0f/POOLK_);
            v = fmaxf(v, 1e-10f);
            partial = fmaf(__logf(v), lw[i], partial);
        }
        #pragma unroll
        for (int off = 32; off > 0; off >>= 1)
            partial += __shfl_down(partial, off, 64);
        if ((tid & 63) == 0) red[tid >> 6] = partial;
        __syncthreads();
        if (tid == 0)
            out[row] = red[0] + red[1] + red[2] + red[3] + lin_b[m];
        __syncthreads();                         // red reused next row
    }
}

extern "C" void kernel_launch(void* const* d_in, const int* in_sizes, int n_in,
                              void* d_out, int out_size, void* d_ws, size_t ws_size,
                              hipStream_t stream) {
    const float* x      = (const float*)d_in[0];
    const float* conv_w = (const float*)d_in[1];
    const float* conv_b = (const float*)d_in[2];
    const float* lin_w  = (const float*)d_in[3];
    const float* lin_b  = (const float*)d_in[4];
    float* out = (float*)d_out;

    dim3 grid((B_ * M_) / 2);       // 8192 blocks, 2 rows each
    dim3 block(256);                // 4 waves
    ChannelScorer_Distributed_39024072851482_kernel<<<grid, block, 0, stream>>>(
        x, conv_w, conv_b, lin_w, lin_b, out);
}

// Round 8
// 192.576 us; speedup vs baseline: 2.1320x; 1.0689x over previous
//
#include <hip/hip_runtime.h>

// Problem constants (from reference)
#define B_     256
#define M_     64
#define T_     1200
#define FT_    10
#define K_     17
#define POOLK_ 75
#define POOLS_ 15
#define TP_    76            // pooled length
#define NSEG_  80            // segments of 15
#define FEAT_  (FT_*TP_)     // 760
#define XLEN_  1312          // padded x~: [0..7]=0, [8..1207]=x, rest 0
#define NQT_   5             // 5 N-tiles of 16 q's (80 q >= 75 needed)
#define PLANE_ 330           // y2 plane stride (>=320), 330%32=10 rotates banks

typedef _Float16 f16;
typedef f16   f16x4 __attribute__((ext_vector_type(4)));
typedef f16   f16x8 __attribute__((ext_vector_type(8)));
typedef float f32x4 __attribute__((ext_vector_type(4)));

// Pin a 128-bit fragment in VGPRs (defeats remat/demotion; r3-proven technique).
#define PIN8(v) do {                                                   \
    f32x4 _t = __builtin_bit_cast(f32x4, (v));                         \
    float _a0=_t[0], _a1=_t[1], _a2=_t[2], _a3=_t[3];                  \
    asm volatile("" : "+v"(_a0), "+v"(_a1), "+v"(_a2), "+v"(_a3));     \
    _t = (f32x4){_a0,_a1,_a2,_a3};                                     \
    (v) = __builtin_bit_cast(f16x8, _t);                               \
} while (0)

// Toeplitz-MFMA conv (math verified r6/r7): t = 256qt+16n+(4khi+j);
// y = wh*xh + wh*xl + wl*xh + b (split f16 precision).
// r8: y2 scratch in PLANE-DEINTERLEAVED layout A(t)=330*(t&3)+(t>>2):
//  - writes: 4x ds_write_b32, lane addrs 64qt+4n+khi+imm = 64 consecutive
//    dwords -> 2-way banks = free (r7's b128 pattern was a forced 8-way:
//    16B-aligned starts use only 8 bank-groups, 16n mod 32 in {0,16}).
//  - reads: segment {15l..15l+14} = 4 planes x 3-4 consecutive dwords,
//    bases precomputed once -> ds_read2-friendly, hash-spread banks.
__global__ __launch_bounds__(128, 4)
void ChannelScorer_Distributed_39024072851482_kernel(
    const float* __restrict__ x,      // (B,1,M,T) -> row-major (B*M, T)
    const float* __restrict__ conv_w, // (FT,1,K) = 170
    const float* __restrict__ conv_b, // (FT,)
    const float* __restrict__ lin_w,  // (M, FEAT)
    const float* __restrict__ lin_b,  // (M,)
    float* __restrict__ out)          // (B,M,1) -> 16384
{
    __shared__ __align__(16) f16 xh[XLEN_];      // 2624 B
    __shared__ __align__(16) f16 xl[XLEN_];      // 2624 B
    __shared__ float wsm[FT_*K_];                // 680 B
    __shared__ float y2[2][4*PLANE_];            // 10560 B wave-private planes
    __shared__ float S[FT_*NSEG_];               // 3200 B segment sums
    __shared__ float red[2];
    // total ~19.7 KB -> 8 blocks/CU (16 waves/CU)

    const int tid = threadIdx.x;
    const int row = blockIdx.x;                  // one row per block
    const int m   = row & (M_-1);

    // ---- stage x -> split f16 (xh, xl), zero-padded ----
    {
        const float4* xr = (const float4*)(x + (size_t)row * T_);
        for (int i = tid; i < XLEN_/4; i += 128) {         // 328 float4 tasks
            float4 v = make_float4(0.f, 0.f, 0.f, 0.f);
            if (i >= 2 && i <= 301) v = xr[i-2];           // x~[4i..] = x[4i-8..]
            f16 h0=(f16)v.x, h1=(f16)v.y, h2=(f16)v.z, h3=(f16)v.w;
            f16 l0=(f16)(v.x-(float)h0), l1=(f16)(v.y-(float)h1),
                l2=(f16)(v.z-(float)h2), l3=(f16)(v.w-(float)h3);
            *(f16x4*)&xh[4*i] = (f16x4){h0,h1,h2,h3};
            *(f16x4*)&xl[4*i] = (f16x4){l0,l1,l2,l3};
        }
        for (int i = tid; i < FT_*K_; i += 128) wsm[i] = conv_w[i];
    }
    __syncthreads();

    const int lane = tid & 63, wid = tid >> 6;   // wid = filter-half (0..1)
    const int n   = lane & 15;                   // B col / A row component
    const int khi = lane >> 4;                   // k-quarter

    // ---- Toeplitz A fragments for this wave's 5 filters (registers, pinned) ----
    f16x8 ah[5], al[5];
    #pragma unroll
    for (int fi = 0; fi < 5; ++fi) {
        const int f = wid*5 + fi;
        #pragma unroll
        for (int j = 0; j < 8; ++j) {
            const int d = 8*khi + j - n;                   // kk - r
            const float wv = (d >= 0 && d < K_) ? wsm[f*K_ + d] : 0.f;
            const f16 h = (f16)wv;
            ah[fi][j] = h;
            al[fi][j] = (f16)(wv - (float)h);
        }
        PIN8(ah[fi]); PIN8(al[fi]);
    }

    // ---- B fragments (col n, kk = 8khi+j), pinned resident ----
    const int boff = 16*n + 8*khi;
    f16x8 bh[NQT_], bl[NQT_];
    #pragma unroll
    for (int qt = 0; qt < NQT_; ++qt) {
        bh[qt] = *(const f16x8*)&xh[256*qt + boff];
        bl[qt] = *(const f16x8*)&xl[256*qt + boff];
        PIN8(bh[qt]); PIN8(bl[qt]);
    }

    float* yw = y2[wid];
    const int wb = 4*n + khi;                    // write base (dwords)

    // gather plane bases: seg = lane, t0 = 15*lane; A(t0+c+4d) = pc_c + d
    const int t0 = 15*lane;
    const int pc0 = ((t0+0)&3)*PLANE_ + ((t0+0)>>2);
    const int pc1 = ((t0+1)&3)*PLANE_ + ((t0+1)>>2);
    const int pc2 = ((t0+2)&3)*PLANE_ + ((t0+2)>>2);
    const int pc3 = ((t0+3)&3)*PLANE_ + ((t0+3)>>2);

    #pragma unroll
    for (int fi = 0; fi < 5; ++fi) {
        const int f = wid*5 + fi;
        const float bf = conv_b[f];              // wave-uniform -> s_load
        // conv: 5 q-tiles, squares scattered to planes (imm offsets only)
        #pragma unroll
        for (int qt = 0; qt < NQT_; ++qt) {
            f32x4 acc = {bf, bf, bf, bf};
            acc = __builtin_amdgcn_mfma_f32_16x16x32_f16(ah[fi], bh[qt], acc, 0, 0, 0);
            acc = __builtin_amdgcn_mfma_f32_16x16x32_f16(ah[fi], bl[qt], acc, 0, 0, 0);
            acc = __builtin_amdgcn_mfma_f32_16x16x32_f16(al[fi], bh[qt], acc, 0, 0, 0);
            yw[wb + 64*qt + 0*PLANE_] = acc[0]*acc[0];   // t=..+0
            yw[wb + 64*qt + 1*PLANE_] = acc[1]*acc[1];   // t=..+1
            yw[wb + 64*qt + 2*PLANE_] = acc[2]*acc[2];   // t=..+2
            yw[wb + 64*qt + 3*PLANE_] = acc[3]*acc[3];   // t=..+3
        }
        // segment gather: seg=lane sums y2(t0..t0+14) via 4 plane-runs
        {
            float s =
                ((yw[pc0+0]+yw[pc0+1]) + (yw[pc0+2]+yw[pc0+3])) +
                ((yw[pc1+0]+yw[pc1+1]) + (yw[pc1+2]+yw[pc1+3])) +
                ((yw[pc2+0]+yw[pc2+1]) + (yw[pc2+2]+yw[pc2+3])) +
                ((yw[pc3+0]+yw[pc3+1]) +  yw[pc3+2]);
            S[f*NSEG_ + lane] = s;
            if (lane < 16) {                     // segs 64..79: t' = t0+960 -> +240 dwords
                float s2 =
                    ((yw[pc0+240]+yw[pc0+241]) + (yw[pc0+242]+yw[pc0+243])) +
                    ((yw[pc1+240]+yw[pc1+241]) + (yw[pc1+242]+yw[pc1+243])) +
                    ((yw[pc2+240]+yw[pc2+241]) + (yw[pc2+242]+yw[pc2+243])) +
                    ((yw[pc3+240]+yw[pc3+241]) +  yw[pc3+242]);
                S[f*NSEG_ + 64 + lane] = s2;
            }
        }
    }
    __syncthreads();

    // ---- pool(5 segs) -> log -> dot with lin_w[m,:] ----
    float partial = 0.f;
    const float* lw = lin_w + (size_t)m * FEAT_;
    for (int i = tid; i < FEAT_; i += 128) {     // 6 iters
        const int f = i / TP_;
        const int p = i - f * TP_;
        const float* Sp = &S[f*NSEG_ + p];
        float v = (Sp[0] + Sp[1] + Sp[2] + Sp[3] + Sp[4]) * (1.0f/POOLK_);
        v = fmaxf(v, 1e-10f);
        partial = fmaf(__logf(v), lw[i], partial);
    }

    // ---- block reduction (2 waves) ----
    #pragma unroll
    for (int off = 32; off > 0; off >>= 1)
        partial += __shfl_down(partial, off, 64);
    if ((tid & 63) == 0) red[wid] = partial;
    __syncthreads();
    if (tid == 0)
        out[row] = red[0] + red[1] + lin_b[m];
}

extern "C" void kernel_launch(void* const* d_in, const int* in_sizes, int n_in,
                              void* d_out, int out_size, void* d_ws, size_t ws_size,
                              hipStream_t stream) {
    const float* x      = (const float*)d_in[0];
    const float* conv_w = (const float*)d_in[1];
    const float* conv_b = (const float*)d_in[2];
    const float* lin_w  = (const float*)d_in[3];
    const float* lin_b  = (const float*)d_in[4];
    float* out = (float*)d_out;

    dim3 grid(B_ * M_);             // 16384 blocks, 1 row each
    dim3 block(128);                // 2 waves
    ChannelScorer_Distributed_39024072851482_kernel<<<grid, block, 0, stream>>>(
        x, conv_w, conv_b, lin_w, lin_b, out);
}

// Round 9
// 175.334 us; speedup vs baseline: 2.3416x; 1.0983x over previous
//
#include <hip/hip_runtime.h>

// Problem constants (from reference)
#define B_     256
#define M_     64
#define T_     1200
#define FT_    10
#define K_     17
#define POOLK_ 75
#define POOLS_ 15
#define TP_    76            // pooled length
#define NSEG_  80            // segments of 15
#define FEAT_  (FT_*TP_)     // 760
#define NT_    5             // 5 MFMA tiles x 16 segments = 80

typedef _Float16 f16;
typedef f16   f16x8 __attribute__((ext_vector_type(8)));
typedef float f32x4 __attribute__((ext_vector_type(4)));

// r9: segment-aligned Toeplitz.  A[u][k'] = w[k'-u] (u = pos-in-segment),
// B[k'][g] = x(15g + k' - 8)  =>  C[u][g] = y(15*g + u) + bias.
// Segment sum S[g] = sum_u C[u][g]^2 is a COLUMN sum of the C fragment:
// 4 in-lane squares + shfl_xor(16) + shfl_xor(32).  The r7/r8 y2 scratch,
// plane writes and stride-15 gathers (the LDS-pipe wall at ~105us) vanish.
// B-frags are filter-independent: built once per row, reused by 10 filters.
// Lane mappings identical to the r6-r8 verified kernels.
__global__ __launch_bounds__(128, 5)
void ChannelScorer_Distributed_39024072851482_kernel(
    const float* __restrict__ x,      // (B,1,M,T) -> row-major (B*M, T)
    const float* __restrict__ conv_w, // (FT,1,K) = 170
    const float* __restrict__ conv_b, // (FT,)
    const float* __restrict__ lin_w,  // (M, FEAT)
    const float* __restrict__ lin_b,  // (M,)
    float* __restrict__ out)          // (B,M,1) -> 16384
{
    __shared__ __align__(16) f16 BH[NT_][64][8];  // 5.1 KB  B-frag hi
    __shared__ __align__(16) f16 BL[NT_][64][8];  // 5.1 KB  B-frag lo
    __shared__ float wsm[FT_*K_];                 // 680 B
    __shared__ float S[FT_][NSEG_];               // 3.2 KB segment sums
    __shared__ float red[2];
    // total ~14.1 KB -> ~11 blocks/CU (22 waves)

    const int tid = threadIdx.x;
    const int row = blockIdx.x;                   // one row per block
    const int m   = row & (M_-1);
    const float* xr = x + (size_t)row * T_;

    // ---- stage weights ----
    for (int i = tid; i < FT_*K_; i += 128) wsm[i] = conv_w[i];

    // ---- build B fragments straight from global (no LDS x image):
    // frag elem j of (tile, lane): x[240*tile + 15*n + 8*khi + j - 8], clamped.
    for (int i = tid; i < NT_*64; i += 128) {     // 320 slots, 2.5/thread
        const int tile = i >> 6, l = i & 63;
        const int n = l & 15, khi = l >> 4;
        const int e0 = 240*tile + 15*n + 8*khi - 8;
        f16x8 hv, lv;
        #pragma unroll
        for (int j = 0; j < 8; ++j) {
            const int e = e0 + j;
            const float v = ((unsigned)e < (unsigned)T_) ? xr[e] : 0.f;
            const f16 h = (f16)v;
            hv[j] = h; lv[j] = (f16)(v - (float)h);
        }
        *(f16x8*)&BH[tile][l][0] = hv;            // dense 16B/lane: conflict-free
        *(f16x8*)&BL[tile][l][0] = lv;
    }
    __syncthreads();

    const int lane = tid & 63, wid = tid >> 6;    // wid = filter-half
    const int n = lane & 15, khi = lane >> 4;

    // ---- conv + square + segment-sum, wave wid: filters wid*5..wid*5+4 ----
    #pragma unroll 1
    for (int fi = 0; fi < 5; ++fi) {
        const int f = wid*5 + fi;
        // A-frag: A[u=lane&15][kk=8*khi+j] = w[kk-u]  (row 15 unused -> dropped in C)
        f16x8 ah, al;
        #pragma unroll
        for (int j = 0; j < 8; ++j) {
            const int d = 8*khi + j - n;
            const float wv = ((unsigned)d <= 16u) ? wsm[f*K_ + d] : 0.f;
            const f16 h = (f16)wv;
            ah[j] = h; al[j] = (f16)(wv - (float)h);
        }
        const float bf = conv_b[f];               // wave-uniform -> s_load
        #pragma unroll
        for (int tile = 0; tile < NT_; ++tile) {
            const f16x8 bh = *(const f16x8*)&BH[tile][lane][0];
            const f16x8 bl = *(const f16x8*)&BL[tile][lane][0];
            f32x4 acc = {bf, bf, bf, bf};
            acc = __builtin_amdgcn_mfma_f32_16x16x32_f16(ah, bh, acc, 0, 0, 0);
            acc = __builtin_amdgcn_mfma_f32_16x16x32_f16(ah, bl, acc, 0, 0, 0);
            acc = __builtin_amdgcn_mfma_f32_16x16x32_f16(al, bh, acc, 0, 0, 0);
            // C rows 4*khi+j = u; row 15 (khi=3,j=3) = next segment's u=0: drop.
            const float q3 = (khi == 3) ? 0.f : acc[3]*acc[3];
            float p = fmaf(acc[0],acc[0], fmaf(acc[1],acc[1],
                      fmaf(acc[2],acc[2], q3)));
            p += __shfl_xor(p, 16, 64);           // sum over khi lanes
            p += __shfl_xor(p, 32, 64);
            if (lane < 16) S[f][16*tile + lane] = p;   // seg g = 16*tile + n
        }
    }
    __syncthreads();

    // ---- pool(5 segs) -> log -> dot with lin_w[m,:] (r3-verified epilogue) ----
    float partial = 0.f;
    const float* lw = lin_w + (size_t)m * FEAT_;
    for (int i = tid; i < FEAT_; i += 128) {      // 6 iters
        const int f = i / TP_;
        const int p = i - f * TP_;
        const float* Sp = &S[f][p];
        float v = (Sp[0] + Sp[1] + Sp[2] + Sp[3] + Sp[4]) * (1.0f/POOLK_);
        v = fmaxf(v, 1e-10f);
        partial = fmaf(__logf(v), lw[i], partial);
    }

    // ---- block reduction (2 waves) ----
    #pragma unroll
    for (int off = 32; off > 0; off >>= 1)
        partial += __shfl_down(partial, off, 64);
    if ((tid & 63) == 0) red[tid >> 6] = partial;
    __syncthreads();
    if (tid == 0)
        out[row] = red[0] + red[1] + lin_b[m];
}

extern "C" void kernel_launch(void* const* d_in, const int* in_sizes, int n_in,
                              void* d_out, int out_size, void* d_ws, size_t ws_size,
                              hipStream_t stream) {
    const float* x      = (const float*)d_in[0];
    const float* conv_w = (const float*)d_in[1];
    const float* conv_b = (const float*)d_in[2];
    const float* lin_w  = (const float*)d_in[3];
    const float* lin_b  = (const float*)d_in[4];
    float* out = (float*)d_out;

    dim3 grid(B_ * M_);             // 16384 blocks, 1 row each
    dim3 block(128);                // 2 waves
    ChannelScorer_Distributed_39024072851482_kernel<<<grid, block, 0, stream>>>(
        x, conv_w, conv_b, lin_w, lin_b, out);
}

// Round 10
// 170.994 us; speedup vs baseline: 2.4011x; 1.0254x over previous
//
#include <hip/hip_runtime.h>

// Problem constants (from reference)
#define B_     256
#define M_     64
#define T_     1200
#define FT_    10
#define K_     17
#define POOLK_ 75
#define POOLS_ 15
#define TP_    76            // pooled length
#define NSEG_  80            // segments of 15
#define FEAT_  (FT_*TP_)     // 760
#define NT_    5             // 5 MFMA tiles x 16 segments = 80

typedef _Float16 f16;
typedef f16   f16x8 __attribute__((ext_vector_type(8)));
typedef float f32x4 __attribute__((ext_vector_type(4)));
typedef float f32x4u __attribute__((ext_vector_type(4), aligned(4)));  // 4B-aligned vec load

// Pin a 128-bit fragment in VGPRs (insurance vs remat; r3/r8 technique).
#define PIN8(v) do {                                                   \
    f32x4 _t = __builtin_bit_cast(f32x4, (v));                         \
    float _a0=_t[0], _a1=_t[1], _a2=_t[2], _a3=_t[3];                  \
    asm volatile("" : "+v"(_a0), "+v"(_a1), "+v"(_a2), "+v"(_a3));     \
    _t = (f32x4){_a0,_a1,_a2,_a3};                                     \
    (v) = __builtin_bit_cast(f16x8, _t);                               \
} while (0)

// r10 = r9's segment-aligned Toeplitz MFMA (math verified r9, passed @2.44e-4)
// with the B-fragment LDS round-trip deleted:
//  - B-frag = 8 consecutive floats from global x at e0 = 240*tile+15n+8khi-8
//    -> built in REGISTERS via two unaligned dwordx4 loads (r9: 320-slot LDS
//    staging + 50 ds_read_b128/wave was the VALU+lgkm critical path).
//  - A-frag clamp removed: wsm2[f][32] zero-padded table, index (d&31) maps
//    negative/overflow d onto the zero tail. 8 LDS addrs reused per filter.
//  - LDS 14.1 -> ~4.5 KB; occupancy becomes VGPR-capped.
__global__ __launch_bounds__(128, 4)
void ChannelScorer_Distributed_39024072851482_kernel(
    const float* __restrict__ x,      // (B,1,M,T) -> row-major (B*M, T)
    const float* __restrict__ conv_w, // (FT,1,K) = 170
    const float* __restrict__ conv_b, // (FT,)
    const float* __restrict__ lin_w,  // (M, FEAT)
    const float* __restrict__ lin_b,  // (M,)
    float* __restrict__ out)          // (B,M,1) -> 16384
{
    __shared__ float wsm2[FT_*32];               // 1.25 KB zero-padded weights
    __shared__ float S[FT_][NSEG_];              // 3.2 KB segment sums
    __shared__ float red[2];
    // total ~4.5 KB

    const int tid = threadIdx.x;
    const int row = blockIdx.x;                  // one row per block
    const int m   = row & (M_-1);
    const float* xr = x + (size_t)row * T_;

    // ---- stage zero-padded weight table ----
    for (int i = tid; i < FT_*32; i += 128) {
        const int f = i >> 5, d = i & 31;
        wsm2[i] = (d < K_) ? conv_w[f*K_ + d] : 0.f;
    }
    __syncthreads();

    const int lane = tid & 63, wid = tid >> 6;   // wid = filter-half
    const int n = lane & 15, khi = lane >> 4;

    // ---- B fragments in registers: elem j = x[240*t + 15n + 8khi - 8 + j] ----
    const int ebase = 15*n + 8*khi - 8;
    f16x8 bh[NT_], bl[NT_];
    #pragma unroll
    for (int t = 0; t < NT_; ++t) {
        const int e0 = 240*t + ebase;
        float v[8];
        // tiles 1..3: compile-time safe (e0 in [232,961], e0+7 <= 968 < 1200)
        bool safe = (t >= 1 && t <= 3);
        if (t == 0) safe = (e0 >= 0);            // only lane (n=0,khi=0) unsafe
        if (t == 4) safe = (e0 + 7 < T_);        // only n=15,khi>=2 unsafe
        if (safe) {
            f32x4u a = *(const f32x4u*)(xr + e0);
            f32x4u b = *(const f32x4u*)(xr + e0 + 4);
            v[0]=a[0]; v[1]=a[1]; v[2]=a[2]; v[3]=a[3];
            v[4]=b[0]; v[5]=b[1]; v[6]=b[2]; v[7]=b[3];
        } else {
            #pragma unroll
            for (int j = 0; j < 8; ++j) {
                const int e = e0 + j;
                v[j] = ((unsigned)e < (unsigned)T_) ? xr[e] : 0.f;
            }
        }
        f16x8 hv, lv;
        #pragma unroll
        for (int j = 0; j < 8; ++j) {
            const f16 h = (f16)v[j];
            hv[j] = h; lv[j] = (f16)(v[j] - (float)h);
        }
        bh[t] = hv; bl[t] = lv;
        PIN8(bh[t]); PIN8(bl[t]);
    }

    // ---- A-frag LDS indices (filter-independent, reused x5) ----
    int widx[8];
    #pragma unroll
    for (int j = 0; j < 8; ++j)
        widx[j] = (8*khi + j - n) & 31;          // negatives/overflow -> zero tail

    // ---- conv + square + segment-sum, wave wid: filters wid*5..wid*5+4 ----
    #pragma unroll 1
    for (int fi = 0; fi < 5; ++fi) {
        const int f = wid*5 + fi;
        const float* wf = &wsm2[f*32];
        f16x8 ah, al;
        #pragma unroll
        for (int j = 0; j < 8; ++j) {
            const float wv = wf[widx[j]];        // no clamp: table zero-padded
            const f16 h = (f16)wv;
            ah[j] = h; al[j] = (f16)(wv - (float)h);
        }
        const float bf = conv_b[f];              // wave-uniform -> s_load
        #pragma unroll
        for (int t = 0; t < NT_; ++t) {
            f32x4 acc = {bf, bf, bf, bf};
            acc = __builtin_amdgcn_mfma_f32_16x16x32_f16(ah, bh[t], acc, 0, 0, 0);
            acc = __builtin_amdgcn_mfma_f32_16x16x32_f16(ah, bl[t], acc, 0, 0, 0);
            acc = __builtin_amdgcn_mfma_f32_16x16x32_f16(al, bh[t], acc, 0, 0, 0);
            // C row 15 (khi=3,j=3) = next segment's u=0: drop from this seg.
            const float q3 = (khi == 3) ? 0.f : acc[3]*acc[3];
            float p = fmaf(acc[0],acc[0], fmaf(acc[1],acc[1],
                      fmaf(acc[2],acc[2], q3)));
            p += __shfl_xor(p, 16, 64);          // sum over khi groups
            p += __shfl_xor(p, 32, 64);
            if (lane < 16) S[f][16*t + lane] = p;     // seg g = 16*t + n
        }
    }
    __syncthreads();

    // ---- pool(5 segs) -> log -> dot with lin_w[m,:] (r3-verified epilogue) ----
    float partial = 0.f;
    const float* lw = lin_w + (size_t)m * FEAT_;
    for (int i = tid; i < FEAT_; i += 128) {     // 6 iters
        const int f = i / TP_;
        const int p = i - f * TP_;
        const float* Sp = &S[f][p];
        float v = (Sp[0] + Sp[1] + Sp[2] + Sp[3] + Sp[4]) * (1.0f/POOLK_);
        v = fmaxf(v, 1e-10f);
        partial = fmaf(__logf(v), lw[i], partial);
    }

    // ---- block reduction (2 waves) ----
    #pragma unroll
    for (int off = 32; off > 0; off >>= 1)
        partial += __shfl_down(partial, off, 64);
    if ((tid & 63) == 0) red[tid >> 6] = partial;
    __syncthreads();
    if (tid == 0)
        out[row] = red[0] + red[1] + lin_b[m];
}

extern "C" void kernel_launch(void* const* d_in, const int* in_sizes, int n_in,
                              void* d_out, int out_size, void* d_ws, size_t ws_size,
                              hipStream_t stream) {
    const float* x      = (const float*)d_in[0];
    const float* conv_w = (const float*)d_in[1];
    const float* conv_b = (const float*)d_in[2];
    const float* lin_w  = (const float*)d_in[3];
    const float* lin_b  = (const float*)d_in[4];
    float* out = (float*)d_out;

    dim3 grid(B_ * M_);             // 16384 blocks, 1 row each
    dim3 block(128);                // 2 waves
    ChannelScorer_Distributed_39024072851482_kernel<<<grid, block, 0, stream>>>(
        x, conv_w, conv_b, lin_w, lin_b, out);
}

// Round 11
// 170.955 us; speedup vs baseline: 2.4016x; 1.0002x over previous
//
#include <hip/hip_runtime.h>

// Problem constants (from reference)
#define B_     256
#define M_     64
#define T_     1200
#define FT_    10
#define K_     17
#define POOLK_ 75
#define POOLS_ 15
#define TP_    76            // pooled length
#define NSEG_  80            // segments of 15
#define FEAT_  (FT_*TP_)     // 760
#define NT_    5             // 5 MFMA tiles x 16 segments = 80

typedef _Float16 f16;
typedef f16   f16x8 __attribute__((ext_vector_type(8)));
typedef float f32x4 __attribute__((ext_vector_type(4)));
typedef float f32x4u __attribute__((ext_vector_type(4), aligned(4)));  // 4B-aligned vec load

// Pin a 128-bit fragment in VGPRs.
#define PIN8(v) do {                                                   \
    f32x4 _t = __builtin_bit_cast(f32x4, (v));                         \
    float _a0=_t[0], _a1=_t[1], _a2=_t[2], _a3=_t[3];                  \
    asm volatile("" : "+v"(_a0), "+v"(_a1), "+v"(_a2), "+v"(_a3));     \
    _t = (f32x4){_a0,_a1,_a2,_a3};                                     \
    (v) = __builtin_bit_cast(f16x8, _t);                               \
} while (0)

// r11 = r10's segment-aligned Toeplitz MFMA with a MINIMAL-LIVE-SET schedule.
// r10 failure mode: VGPR=40 < the 10 pinned B-frags -> allocator spilled/
// rebuilt them per filter (VALU busy 2.7x the work floor).  Fix: tile-OUTER,
// filter-inner, fully unrolled.  B-frag lives for ONE tile iteration (8 VGPR,
// nothing to spill); A-frags (5 filters) built once and kept (40 VGPR ask,
// bounded LDS-rebuild fallback if demoted).  Full unroll lets tile t+1's two
// global dwordx4 loads hoist under tile t's MFMAs.
__global__ __launch_bounds__(128, 4)
void ChannelScorer_Distributed_39024072851482_kernel(
    const float* __restrict__ x,      // (B,1,M,T) -> row-major (B*M, T)
    const float* __restrict__ conv_w, // (FT,1,K) = 170
    const float* __restrict__ conv_b, // (FT,)
    const float* __restrict__ lin_w,  // (M, FEAT)
    const float* __restrict__ lin_b,  // (M,)
    float* __restrict__ out)          // (B,M,1) -> 16384
{
    __shared__ float wsm2[FT_*32];               // 1.25 KB zero-padded weights
    __shared__ float S[FT_][NSEG_];              // 3.2 KB segment sums
    __shared__ float red[2];
    // total ~4.5 KB

    const int tid = threadIdx.x;
    const int row = blockIdx.x;                  // one row per block
    const int m   = row & (M_-1);
    const float* xr = x + (size_t)row * T_;

    // ---- stage zero-padded weight table ----
    for (int i = tid; i < FT_*32; i += 128) {
        const int f = i >> 5, d = i & 31;
        wsm2[i] = (d < K_) ? conv_w[f*K_ + d] : 0.f;
    }
    __syncthreads();

    const int lane = tid & 63, wid = tid >> 6;   // wid = filter-half
    const int n = lane & 15, khi = lane >> 4;
    const float m3 = (khi == 3) ? 0.f : 1.f;     // drop C row 15 (next seg's u=0)

    // ---- A-frags for this wave's 5 filters, built once (ask: resident) ----
    f16x8 ah[5], al[5];
    float bf[5];
    #pragma unroll
    for (int fi = 0; fi < 5; ++fi) {
        const int f = wid*5 + fi;
        const float* wf = &wsm2[f*32];
        #pragma unroll
        for (int j = 0; j < 8; ++j) {
            const float wv = wf[(8*khi + j - n) & 31];   // wrap -> zero tail
            const f16 h = (f16)wv;
            ah[fi][j] = h; al[fi][j] = (f16)(wv - (float)h);
        }
        PIN8(ah[fi]); PIN8(al[fi]);
        bf[fi] = conv_b[f];                      // wave-uniform -> s_load
    }

    // ---- conv: tile-outer (B live one iteration), filter-inner ----
    const int ebase = 15*n + 8*khi - 8;
    #pragma unroll
    for (int t = 0; t < NT_; ++t) {
        const int e0 = 240*t + ebase;
        float v[8];
        bool safe = (t >= 1 && t <= 3);          // e0 in [232,961], +7 < 1200
        if (t == 0) safe = (e0 >= 0);            // only lane n=0,khi=0 unsafe
        if (t == 4) safe = (e0 + 7 < T_);        // only n=15,khi>=2 unsafe
        if (safe) {
            f32x4u a = *(const f32x4u*)(xr + e0);
            f32x4u b = *(const f32x4u*)(xr + e0 + 4);
            v[0]=a[0]; v[1]=a[1]; v[2]=a[2]; v[3]=a[3];
            v[4]=b[0]; v[5]=b[1]; v[6]=b[2]; v[7]=b[3];
        } else {
            #pragma unroll
            for (int j = 0; j < 8; ++j) {
                const int e = e0 + j;
                v[j] = ((unsigned)e < (unsigned)T_) ? xr[e] : 0.f;
            }
        }
        f16x8 bh, bl;
        #pragma unroll
        for (int j = 0; j < 8; ++j) {
            const f16 h = (f16)v[j];
            bh[j] = h; bl[j] = (f16)(v[j] - (float)h);
        }

        #pragma unroll
        for (int fi = 0; fi < 5; ++fi) {
            f32x4 acc = {bf[fi], bf[fi], bf[fi], bf[fi]};
            acc = __builtin_amdgcn_mfma_f32_16x16x32_f16(ah[fi], bh, acc, 0, 0, 0);
            acc = __builtin_amdgcn_mfma_f32_16x16x32_f16(ah[fi], bl, acc, 0, 0, 0);
            acc = __builtin_amdgcn_mfma_f32_16x16x32_f16(al[fi], bh, acc, 0, 0, 0);
            float p = fmaf(acc[0],acc[0], fmaf(acc[1],acc[1],
                      fmaf(acc[2],acc[2], acc[3]*acc[3]*m3)));
            p += __shfl_xor(p, 16, 64);          // sum over khi groups
            p += __shfl_xor(p, 32, 64);
            if (lane < 16) S[wid*5 + fi][16*t + lane] = p;   // seg g = 16t + n
        }
    }
    __syncthreads();

    // ---- pool(5 segs) -> log -> dot with lin_w[m,:] (verified epilogue) ----
    float partial = 0.f;
    const float* lw = lin_w + (size_t)m * FEAT_;
    for (int i = tid; i < FEAT_; i += 128) {     // 6 iters
        const int f = i / TP_;
        const int p = i - f * TP_;
        const float* Sp = &S[f][p];
        float v = (Sp[0] + Sp[1] + Sp[2] + Sp[3] + Sp[4]) * (1.0f/POOLK_);
        v = fmaxf(v, 1e-10f);
        partial = fmaf(__logf(v), lw[i], partial);
    }

    // ---- block reduction (2 waves) ----
    #pragma unroll
    for (int off = 32; off > 0; off >>= 1)
        partial += __shfl_down(partial, off, 64);
    if ((tid & 63) == 0) red[tid >> 6] = partial;
    __syncthreads();
    if (tid == 0)
        out[row] = red[0] + red[1] + lin_b[m];
}

extern "C" void kernel_launch(void* const* d_in, const int* in_sizes, int n_in,
                              void* d_out, int out_size, void* d_ws, size_t ws_size,
                              hipStream_t stream) {
    const float* x      = (const float*)d_in[0];
    const float* conv_w = (const float*)d_in[1];
    const float* conv_b = (const float*)d_in[2];
    const float* lin_w  = (const float*)d_in[3];
    const float* lin_b  = (const float*)d_in[4];
    float* out = (float*)d_out;

    dim3 grid(B_ * M_);             // 16384 blocks, 1 row each
    dim3 block(128);                // 2 waves
    ChannelScorer_Distributed_39024072851482_kernel<<<grid, block, 0, stream>>>(
        x, conv_w, conv_b, lin_w, lin_b, out);
}